// Round 1
// baseline (946.843 us; speedup 1.0000x reference)
//
#include <hip/hip_runtime.h>
#include <hip/hip_bf16.h>

#define DK 256      // inner dim (d)
#define NC 128      // GEMM output cols (4K)
#define EPSV 1e-6f

typedef __bf16 bf16x8 __attribute__((ext_vector_type(8)));
typedef float f32x4 __attribute__((ext_vector_type(4)));

// ws layout (floats): [0..31] Usum, [32..63] s, [64..1087] VtZ, [1088] D

// Kernel 1: X = relu(x@W + b). U -> out[:,0:32], T -> out[:,32:64];
// accumulate Usum, s, VtZ into accg.
// Block = 512 thr = 8 waves: wave -> (mw = wave>>1 row-group, nw = wave&1 col-half).
// B-fragments (bf16 W) live in registers: 8 kk x 4 ntl x 4 VGPR = 128 VGPRs.
__global__ __launch_bounds__(512, 2) void k_gemm(
    const float* __restrict__ x, const float* __restrict__ W,
    const float* __restrict__ bias, float* __restrict__ out,
    float* __restrict__ accg, int N)
{
  __shared__ float Vs[64 * 36];   // pitch 36: conflict-free writes, b128-aligned reads
  __shared__ float Zs[64 * 36];
  __shared__ float redS[64];

  const int tid  = threadIdx.x;
  const int wave = tid >> 6;
  const int lane = tid & 63;
  const int quad = lane >> 4;
  const int l16  = lane & 15;
  const int mw   = wave >> 1;   // 0..3: 16-row group within 64-row chunk
  const int nw   = wave & 1;    // 0..1: 64-col half

  // --- load B fragments + bias into registers (one-time; W is L2/L3-hot) ---
  // B layout for mfma_f32_16x16x32_bf16: lane holds B[k = quad*8+j][n = l16]
  bf16x8 Bf[8][4];
  float bias4[4];
  #pragma unroll
  for (int ntl = 0; ntl < 4; ++ntl) {
    const int n = nw * 64 + ntl * 16 + l16;
    bias4[ntl] = bias[n];
    #pragma unroll
    for (int kk = 0; kk < 8; ++kk) {
      const int k0 = kk * 32 + quad * 8;
      bf16x8 f;
      #pragma unroll
      for (int j = 0; j < 8; ++j) f[j] = (__bf16)W[(size_t)(k0 + j) * NC + n];
      Bf[kk][ntl] = f;
    }
  }

  float usumv[2] = {0.f, 0.f};
  float ssumv[2] = {0.f, 0.f};
  // VtZ ownership: cell = (ck, cj..cj+3), two threads split the 64 rows
  const int cell = tid >> 1;
  const int rh   = tid & 1;
  const int ck   = cell >> 3;        // 0..31
  const int cj   = (cell & 7) * 4;   // 0,4,..,28
  float vtz[4] = {0.f, 0.f, 0.f, 0.f};

  const int nchunks = (N + 63) >> 6;
  for (int c = blockIdx.x; c < nchunks; c += gridDim.x) {
    const int rbase = c * 64;
    const int arow  = rbase + mw * 16 + l16;   // A-fragment row: m = l16
    const bool rv   = arow < N;
    const float* xr = x + (size_t)arow * DK;

    f32x4 acc[4];
    #pragma unroll
    for (int t = 0; t < 4; ++t) acc[t] = (f32x4){0.f, 0.f, 0.f, 0.f};

    #pragma unroll
    for (int kk = 0; kk < 8; ++kk) {
      const int koff = kk * 32 + quad * 8;     // A: k = quad*8 + j
      f32x4 a0 = {0.f,0.f,0.f,0.f}, a1 = {0.f,0.f,0.f,0.f};
      if (rv) {
        a0 = *(const f32x4*)(xr + koff);       // 32B contiguous per lane
        a1 = *(const f32x4*)(xr + koff + 4);
      }
      bf16x8 af;
      af[0] = (__bf16)a0.x; af[1] = (__bf16)a0.y;
      af[2] = (__bf16)a0.z; af[3] = (__bf16)a0.w;
      af[4] = (__bf16)a1.x; af[5] = (__bf16)a1.y;
      af[6] = (__bf16)a1.z; af[7] = (__bf16)a1.w;
      #pragma unroll
      for (int ntl = 0; ntl < 4; ++ntl)
        acc[ntl] = __builtin_amdgcn_mfma_f32_16x16x32_bf16(af, Bf[kk][ntl], acc[ntl], 0, 0, 0);
    }

    // epilogue: C/D layout col = l16, row = quad*4 + reg
    #pragma unroll
    for (int ntl = 0; ntl < 4; ++ntl) {
      #pragma unroll
      for (int r = 0; r < 4; ++r) {
        const int lrow = mw * 16 + quad * 4 + r;
        const int grow = rbase + lrow;
        const bool ok = grow < N;
        float v = acc[ntl][r] + bias4[ntl];
        v = fmaxf(v, 0.f);
        if (!ok) v = 0.f;                      // mask tail rows out of reductions
        if (nw == 0) {
          if (ntl < 2) {                       // U: X cols 0..31
            if (ok) out[(size_t)grow * 64 + ntl * 16 + l16] = v;
            usumv[ntl] += v;
          } else {                             // V: X cols 32..63
            ssumv[ntl - 2] += v;
            Vs[lrow * 36 + (ntl - 2) * 16 + l16] = v;
          }
        } else {
          if (ntl < 2) {                       // Z: X cols 64..95
            Zs[lrow * 36 + ntl * 16 + l16] = v;
          } else {                             // T: X cols 96..127 -> out cols 32..63
            if (ok) out[(size_t)grow * 64 + 32 + (ntl - 2) * 16 + l16] = v;
          }
        }
      }
    }
    __syncthreads();
    // VtZ partial over this chunk's 32-row half
    const int rr0 = rh * 32;
    #pragma unroll 4
    for (int r = rr0; r < rr0 + 32; ++r) {
      const float vv = Vs[r * 36 + ck];
      vtz[0] += vv * Zs[r * 36 + cj + 0];
      vtz[1] += vv * Zs[r * 36 + cj + 1];
      vtz[2] += vv * Zs[r * 36 + cj + 2];
      vtz[3] += vv * Zs[r * 36 + cj + 3];
    }
    __syncthreads();   // before next chunk overwrites Vs/Zs
  }

  // block-level reduce of Usum/s, then one global atomicAdd set
  if (tid < 64) redS[tid] = 0.f;
  __syncthreads();
  if (nw == 0) {
    atomicAdd(&redS[l16],      usumv[0]);
    atomicAdd(&redS[16 + l16], usumv[1]);
    atomicAdd(&redS[32 + l16], ssumv[0]);
    atomicAdd(&redS[48 + l16], ssumv[1]);
  }
  __syncthreads();
  if (tid < 64) atomicAdd(&accg[tid], redS[tid]);
  atomicAdd(&accg[64 + ck * 32 + cj + 0], vtz[0]);
  atomicAdd(&accg[64 + ck * 32 + cj + 1], vtz[1]);
  atomicAdd(&accg[64 + ck * 32 + cj + 2], vtz[2]);
  atomicAdd(&accg[64 + ck * 32 + cj + 3], vtz[3]);
}

// Kernel 2: D = 1 / (Usum . s / N + EPS)
__global__ void k_norm(float* __restrict__ accg, int N) {
  const int t = threadIdx.x;
  float p = 0.f;
  if (t < 32) p = accg[t] * accg[32 + t];
  #pragma unroll
  for (int off = 16; off >= 1; off >>= 1) p += __shfl_down(p, off);
  if (t == 0) accg[1088] = 1.0f / (p / (float)N + EPSV);
}

// Kernel 3: in-place out[:,0:32] = U @ (VtZ * D). U was parked in those columns.
__global__ __launch_bounds__(256) void k_res(float* __restrict__ out,
                                             const float* __restrict__ accg, int N) {
  __shared__ float Ms[32 * 33];
  __shared__ float Us[64 * 33];
  const float D = accg[1088];
  for (int i = threadIdx.x; i < 1024; i += 256)
    Ms[(i >> 5) * 33 + (i & 31)] = accg[64 + i] * D;
  __syncthreads();
  const int j  = threadIdx.x & 31;
  const int r0 = threadIdx.x >> 5;  // 0..7
  const int ngroups = (N + 63) >> 6;
  for (int g = blockIdx.x; g < ngroups; g += gridDim.x) {
    const int rbase = g * 64;
    #pragma unroll
    for (int i = 0; i < 8; ++i) {
      const int lr = r0 + i * 8;
      const int row = rbase + lr;
      Us[lr * 33 + j] = (row < N) ? out[(size_t)row * 64 + j] : 0.f;
    }
    __syncthreads();     // all U staged before any in-place overwrite
    #pragma unroll
    for (int i = 0; i < 8; ++i) {
      const int lr = r0 + i * 8;
      const int row = rbase + lr;
      if (row < N) {
        float a = 0.f;
        #pragma unroll
        for (int k = 0; k < 32; ++k) a += Us[lr * 33 + k] * Ms[k * 33 + j];
        out[(size_t)row * 64 + j] = a;
      }
    }
    __syncthreads();     // before next group's staging reuses Us
  }
}

extern "C" void kernel_launch(void* const* d_in, const int* in_sizes, int n_in,
                              void* d_out, int out_size, void* d_ws, size_t ws_size,
                              hipStream_t stream) {
  const float* x    = (const float*)d_in[0];
  const float* W    = (const float*)d_in[1];
  const float* b    = (const float*)d_in[2];
  float* out  = (float*)d_out;
  float* accg = (float*)d_ws;
  const int N = in_sizes[0] / DK;

  hipMemsetAsync(accg, 0, 1089 * sizeof(float), stream);  // zero accumulators (capture-safe)
  hipLaunchKernelGGL(k_gemm, dim3(256),  dim3(512), 0, stream, x, W, b, out, accg, N);
  hipLaunchKernelGGL(k_norm, dim3(1),    dim3(64),  0, stream, accg, N);
  hipLaunchKernelGGL(k_res,  dim3(1024), dim3(256), 0, stream, out, accg, N);
}

// Round 2
// 784.718 us; speedup vs baseline: 1.2066x; 1.2066x over previous
//
#include <hip/hip_runtime.h>
#include <hip/hip_bf16.h>

#define DK 256      // inner dim (d)
#define NC 128      // GEMM output cols (4K)
#define EPSV 1e-6f

typedef __bf16 bf16x8 __attribute__((ext_vector_type(8)));
typedef __bf16 bf16x4 __attribute__((ext_vector_type(4)));
typedef float f32x4 __attribute__((ext_vector_type(4)));

// ws layout (floats): [0..31] Usum, [32..63] s, [64..1087] VtZ, [1088] D

// Kernel 1: X = relu(x@W + b). U -> out[:,0:32], T -> out[:,32:64];
// accumulate Usum, s (VALU partials) and VtZ (MFMA) into accg.
// Block = 512 thr = 8 waves: wave -> (mw = wave>>1 row-group, nw = wave&1 col-half).
// W lives in LDS as pre-converted bf16 MFMA B-fragments (64 KB), loaded once.
__global__ __launch_bounds__(512, 4) void k_gemm(
    const float* __restrict__ x, const float* __restrict__ W,
    const float* __restrict__ bias, float* __restrict__ out,
    float* __restrict__ accg, int N)
{
  // B-fragment layout: frag index f = (kk*4+quad)*128 + n, 8 bf16 each (16 B)
  __shared__ __bf16 Wlds[32768];          // 64 KB
  __shared__ __bf16 Vt[32 * 72];          // V^T, column-major [col][row], pitch 72
  __shared__ __bf16 Zt[32 * 72];          // Z^T
  __shared__ float  redS[64];

  const int tid  = threadIdx.x;
  const int wave = tid >> 6;
  const int lane = tid & 63;
  const int quad = lane >> 4;
  const int l16  = lane & 15;
  const int mw   = wave >> 1;   // 0..3: 16-row group within 64-row chunk
  const int nw   = wave & 1;    // 0..1: 64-col half

  // --- stage W into LDS as bf16 fragments (once per block; W is L2-hot) ---
  for (int f = tid; f < 4096; f += 512) {
    const int n  = f & 127;
    const int qk = f >> 7;                 // kk*4 + quad
    const int k0 = (qk >> 2) * 32 + (qk & 3) * 8;
    bf16x8 w;
    #pragma unroll
    for (int j = 0; j < 8; ++j) w[j] = (__bf16)W[(size_t)(k0 + j) * NC + n];
    *(bf16x8*)&Wlds[f * 8] = w;
  }
  float bias4[4];
  #pragma unroll
  for (int ntl = 0; ntl < 4; ++ntl) bias4[ntl] = bias[nw * 64 + ntl * 16 + l16];
  __syncthreads();

  float usumv[2] = {0.f, 0.f};
  float ssumv[2] = {0.f, 0.f};
  f32x4 vacc = (f32x4){0.f, 0.f, 0.f, 0.f};   // VtZ tile accumulator (waves 0..3)
  const int mt = wave >> 1, nt = wave & 1;    // VtZ tile coords for wave<4

  const int nchunks = (N + 63) >> 6;
  for (int c = blockIdx.x; c < nchunks; c += gridDim.x) {
    const int rbase = c << 6;
    const int arow  = rbase + mw * 16 + l16;   // A-fragment row: m = l16
    const bool rv   = arow < N;
    const float* xr = x + (size_t)arow * DK;

    // issue all x loads for this chunk upfront (16 VMEM in flight)
    f32x4 xv[16];
    #pragma unroll
    for (int kk = 0; kk < 8; ++kk) {
      const int koff = kk * 32 + quad * 8;     // A: k = quad*8 + j
      xv[2 * kk]     = rv ? *(const f32x4*)(xr + koff)     : (f32x4){0.f,0.f,0.f,0.f};
      xv[2 * kk + 1] = rv ? *(const f32x4*)(xr + koff + 4) : (f32x4){0.f,0.f,0.f,0.f};
    }

    f32x4 acc[4];
    #pragma unroll
    for (int t = 0; t < 4; ++t) acc[t] = (f32x4){0.f, 0.f, 0.f, 0.f};

    #pragma unroll
    for (int kk = 0; kk < 8; ++kk) {
      bf16x8 af;
      af[0] = (__bf16)xv[2*kk].x;   af[1] = (__bf16)xv[2*kk].y;
      af[2] = (__bf16)xv[2*kk].z;   af[3] = (__bf16)xv[2*kk].w;
      af[4] = (__bf16)xv[2*kk+1].x; af[5] = (__bf16)xv[2*kk+1].y;
      af[6] = (__bf16)xv[2*kk+1].z; af[7] = (__bf16)xv[2*kk+1].w;
      #pragma unroll
      for (int ntl = 0; ntl < 4; ++ntl) {
        const bf16x8 bf = *(const bf16x8*)&Wlds[(((kk << 2) | quad) * 128
                                                + nw * 64 + ntl * 16 + l16) * 8];
        acc[ntl] = __builtin_amdgcn_mfma_f32_16x16x32_bf16(af, bf, acc[ntl], 0, 0, 0);
      }
    }

    // epilogue: C/D layout col = l16, row = quad*4 + r
    #pragma unroll
    for (int ntl = 0; ntl < 4; ++ntl) {
      float v4[4];
      #pragma unroll
      for (int r = 0; r < 4; ++r) {
        const int grow = rbase + mw * 16 + quad * 4 + r;
        float v = acc[ntl][r] + bias4[ntl];
        v = fmaxf(v, 0.f);
        if (grow >= N) v = 0.f;                // mask tail rows out of reductions
        v4[r] = v;
      }
      const int grow0 = rbase + mw * 16 + quad * 4;
      if (nw == 0) {
        if (ntl < 2) {                         // U: X cols 0..31 -> out cols 0..31
          #pragma unroll
          for (int r = 0; r < 4; ++r) {
            if (grow0 + r < N) out[(size_t)(grow0 + r) * 64 + ntl * 16 + l16] = v4[r];
            usumv[ntl] += v4[r];
          }
        } else {                               // V: X cols 32..63 -> Vt (bf16, col-major)
          ssumv[ntl - 2] += v4[0] + v4[1] + v4[2] + v4[3];
          bf16x4 pv;
          pv[0] = (__bf16)v4[0]; pv[1] = (__bf16)v4[1];
          pv[2] = (__bf16)v4[2]; pv[3] = (__bf16)v4[3];
          const int col = (ntl - 2) * 16 + l16;
          const int lrow = mw * 16 + quad * 4;
          *(bf16x4*)&Vt[col * 72 + lrow] = pv;
        }
      } else {
        if (ntl < 2) {                         // Z: X cols 64..95 -> Zt
          bf16x4 pv;
          pv[0] = (__bf16)v4[0]; pv[1] = (__bf16)v4[1];
          pv[2] = (__bf16)v4[2]; pv[3] = (__bf16)v4[3];
          const int col = ntl * 16 + l16;
          const int lrow = mw * 16 + quad * 4;
          *(bf16x4*)&Zt[col * 72 + lrow] = pv;
        } else {                               // T: X cols 96..127 -> out cols 32..63
          #pragma unroll
          for (int r = 0; r < 4; ++r)
            if (grow0 + r < N) out[(size_t)(grow0 + r) * 64 + 32 + (ntl - 2) * 16 + l16] = v4[r];
        }
      }
    }
    __syncthreads();
    // VtZ += V^T @ Z over this chunk's 64 rows: waves 0..3 own one 16x16 tile each
    if (wave < 4) {
      #pragma unroll
      for (int ks = 0; ks < 2; ++ks) {
        const bf16x8 av = *(const bf16x8*)&Vt[(mt * 16 + l16) * 72 + ks * 32 + quad * 8];
        const bf16x8 bz = *(const bf16x8*)&Zt[(nt * 16 + l16) * 72 + ks * 32 + quad * 8];
        vacc = __builtin_amdgcn_mfma_f32_16x16x32_bf16(av, bz, vacc, 0, 0, 0);
      }
    }
    __syncthreads();   // before next chunk overwrites Vt/Zt
  }

  // block-level reduce of Usum/s, then one global atomicAdd set
  if (tid < 64) redS[tid] = 0.f;
  __syncthreads();
  if (nw == 0) {
    atomicAdd(&redS[l16],      usumv[0]);
    atomicAdd(&redS[16 + l16], usumv[1]);
    atomicAdd(&redS[32 + l16], ssumv[0]);
    atomicAdd(&redS[48 + l16], ssumv[1]);
  }
  __syncthreads();
  if (tid < 64) atomicAdd(&accg[tid], redS[tid]);
  if (wave < 4) {
    #pragma unroll
    for (int r = 0; r < 4; ++r)
      atomicAdd(&accg[64 + (mt * 16 + quad * 4 + r) * 32 + nt * 16 + l16], vacc[r]);
  }
}

// Kernel 2: D = 1 / (Usum . s / N + EPS)
__global__ void k_norm(float* __restrict__ accg, int N) {
  const int t = threadIdx.x;
  float p = 0.f;
  if (t < 32) p = accg[t] * accg[32 + t];
  #pragma unroll
  for (int off = 16; off >= 1; off >>= 1) p += __shfl_down(p, off);
  if (t == 0) accg[1088] = 1.0f / (p / (float)N + EPSV);
}

// Kernel 3: in-place out[:,0:32] = U @ (VtZ * D). One block per 64-row group.
__global__ __launch_bounds__(256) void k_res(float* __restrict__ out,
                                             const float* __restrict__ accg, int N) {
  __shared__ float Ms[32 * 33];
  __shared__ float Us[64 * 33];
  const float D = accg[1088];
  for (int i = threadIdx.x; i < 1024; i += 256)
    Ms[(i >> 5) * 33 + (i & 31)] = accg[64 + i] * D;
  const int j  = threadIdx.x & 31;
  const int r0 = threadIdx.x >> 5;  // 0..7
  const int rbase = blockIdx.x * 64;
  #pragma unroll
  for (int i = 0; i < 8; ++i) {
    const int lr = r0 + i * 8;
    const int row = rbase + lr;
    Us[lr * 33 + j] = (row < N) ? out[(size_t)row * 64 + j] : 0.f;
  }
  __syncthreads();     // Ms ready + all U staged before any in-place overwrite
  #pragma unroll
  for (int i = 0; i < 8; ++i) {
    const int lr = r0 + i * 8;
    const int row = rbase + lr;
    if (row < N) {
      float a = 0.f;
      #pragma unroll
      for (int k = 0; k < 32; ++k) a += Us[lr * 33 + k] * Ms[k * 33 + j];
      out[(size_t)row * 64 + j] = a;
    }
  }
}

extern "C" void kernel_launch(void* const* d_in, const int* in_sizes, int n_in,
                              void* d_out, int out_size, void* d_ws, size_t ws_size,
                              hipStream_t stream) {
  const float* x    = (const float*)d_in[0];
  const float* W    = (const float*)d_in[1];
  const float* b    = (const float*)d_in[2];
  float* out  = (float*)d_out;
  float* accg = (float*)d_ws;
  const int N = in_sizes[0] / DK;
  const int ngroups = (N + 63) >> 6;

  hipMemsetAsync(accg, 0, 1089 * sizeof(float), stream);  // zero accumulators (capture-safe)
  hipLaunchKernelGGL(k_gemm, dim3(512),     dim3(512), 0, stream, x, W, b, out, accg, N);
  hipLaunchKernelGGL(k_norm, dim3(1),       dim3(64),  0, stream, accg, N);
  hipLaunchKernelGGL(k_res,  dim3(ngroups), dim3(256), 0, stream, out, accg, N);
}